// Round 1
// baseline (2045.213 us; speedup 1.0000x reference)
//
#include <hip/hip_runtime.h>
#include <hip/hip_bf16.h>

#define NN 4096
#define KK 64
#define AA 8
#define DD 128
#define CHUNK 16
#define NCHUNK (KK / CHUNK)

// [2 rows x 4 cols] register-tile GEMM helper: acc[j][c] += sum_i x_j[i] * Wg[i*128 + c]
template <int K4>
__device__ __forceinline__ void gemm_2x4(const float* __restrict__ xr0,
                                         const float* __restrict__ xr1,
                                         const float* __restrict__ Wg,
                                         float acc[2][4])
{
#pragma unroll 4
    for (int i4 = 0; i4 < K4; ++i4) {
        float xv[2][4], wv[4][4];
        {
            float4 v0 = *(const float4*)&xr0[i4 * 4];
            float4 v1 = *(const float4*)&xr1[i4 * 4];
            xv[0][0] = v0.x; xv[0][1] = v0.y; xv[0][2] = v0.z; xv[0][3] = v0.w;
            xv[1][0] = v1.x; xv[1][1] = v1.y; xv[1][2] = v1.z; xv[1][3] = v1.w;
        }
#pragma unroll
        for (int u = 0; u < 4; ++u) {
            float4 v = *(const float4*)&Wg[(size_t)(i4 * 4 + u) * DD];
            wv[u][0] = v.x; wv[u][1] = v.y; wv[u][2] = v.z; wv[u][3] = v.w;
        }
#pragma unroll
        for (int j = 0; j < 2; ++j)
#pragma unroll
            for (int c = 0; c < 4; ++c)
#pragma unroll
                for (int u = 0; u < 4; ++u)
                    acc[j][c] = fmaf(xv[j][u], wv[u][c], acc[j][c]);
    }
}

__launch_bounds__(256, 2)
__global__ void l2agg_kernel(
    const int* __restrict__ nodes,
    const int* __restrict__ paths_rel,
    const int* __restrict__ paths_nbr,
    const int* __restrict__ attrs,
    const float* __restrict__ u2e,
    const float* __restrict__ r2e,
    const float* __restrict__ ua2e,
    const float* __restrict__ W1,
    const float* __restrict__ b1,
    const float* __restrict__ W2,
    const float* __restrict__ b2,
    const float* __restrict__ A1,
    const float* __restrict__ ab1,
    const float* __restrict__ A2,
    const float* __restrict__ ab2,
    const float* __restrict__ A3,
    const float* __restrict__ ab3,
    float* __restrict__ out)
{
    // xbuf is multi-use per chunk:
    //   [0:8192)  x tile      16 x 512 fp32 (32 KB)
    //   [0:4096)  h1 tile     16 x 256 (after sync, x dead)
    //   [4096:6144) a1 tile   16 x 128
    //   [6144:8192) a2 tile   16 x 128
    __shared__ float xbuf[CHUNK * 512];
    __shared__ float h2s[KK * DD];      // 32 KB, persists to final reduce
    __shared__ float selfe[DD];
    __shared__ float s1[DD];
    __shared__ float a3s[DD];
    __shared__ float logits[KK];
    __shared__ float wts[KK];

    const int n    = blockIdx.x;
    const int tid  = threadIdx.x;
    const int node = nodes[n];

    if (tid < 32) {
        *(float4*)&selfe[tid * 4] = *(const float4*)&u2e[(size_t)node * DD + tid * 4];
        *(float4*)&a3s[tid * 4]   = *(const float4*)&A3[tid * 4];
    }
    __syncthreads();

    // s1 = ab1 + selfe @ A1[128:256, :]   (hoisted per node; read after later syncs)
    if (tid < DD) {
        float acc = ab1[tid];
#pragma unroll 4
        for (int i = 0; i < DD; ++i)
            acc = fmaf(selfe[i], A1[(size_t)(DD + i) * DD + tid], acc);
        s1[tid] = acc;
    }

    for (int ch = 0; ch < NCHUNK; ++ch) {
        // ---------- stage x[16][512] into LDS ----------
        {
            const int p  = tid >> 4;   // path within chunk 0..15
            const int t  = tid & 15;   // 16 threads per path, 8 floats each
            const int k  = ch * CHUNK + p;
            const int pk = n * KK + k;
            const int i0 = paths_rel[pk * 2 + 0];
            const int i1 = paths_rel[pk * 2 + 1];
            const int nb = paths_nbr[pk];
            const int o  = t * 8;

            float4 r1a = *(const float4*)&r2e[(size_t)i0 * DD + o];
            float4 r1b = *(const float4*)&r2e[(size_t)i0 * DD + o + 4];
            float4 r2a = *(const float4*)&r2e[(size_t)i1 * DD + o];
            float4 r2b = *(const float4*)&r2e[(size_t)i1 * DD + o + 4];
            float4 nea = *(const float4*)&u2e[(size_t)nb * DD + o];
            float4 neb = *(const float4*)&u2e[(size_t)nb * DD + o + 4];
            float4 aea = make_float4(0.f, 0.f, 0.f, 0.f);
            float4 aeb = make_float4(0.f, 0.f, 0.f, 0.f);
#pragma unroll
            for (int a = 0; a < AA; ++a) {
                const int ai = attrs[pk * AA + a];
                float4 va = *(const float4*)&ua2e[(size_t)ai * DD + o];
                float4 vb = *(const float4*)&ua2e[(size_t)ai * DD + o + 4];
                aea.x += va.x; aea.y += va.y; aea.z += va.z; aea.w += va.w;
                aeb.x += vb.x; aeb.y += vb.y; aeb.z += vb.z; aeb.w += vb.w;
            }
            float* xr = &xbuf[p * 512];
            *(float4*)&xr[o]           = r1a; *(float4*)&xr[o + 4]       = r1b;
            *(float4*)&xr[128 + o]     = r2a; *(float4*)&xr[128 + o + 4] = r2b;
            *(float4*)&xr[256 + o]     = nea; *(float4*)&xr[256 + o + 4] = neb;
            *(float4*)&xr[384 + o]     = aea; *(float4*)&xr[384 + o + 4] = aeb;
        }
        __syncthreads();

        // ---------- GEMM1: h1 = relu(x @ W1 + b1)  [16x512]@[512x256] ----------
        {
            const int pg = tid >> 6;   // wave id -> 4 paths (wave-uniform LDS reads)
            const int cg = tid & 63;   // 64 col groups x 4 cols = 256 cols
            float acc[4][4];
#pragma unroll
            for (int j = 0; j < 4; ++j)
#pragma unroll
                for (int c = 0; c < 4; ++c) acc[j][c] = 0.f;

#pragma unroll 2
            for (int i4 = 0; i4 < 128; ++i4) {
                float xv[4][4], wv[4][4];
#pragma unroll
                for (int j = 0; j < 4; ++j) {
                    float4 v = *(const float4*)&xbuf[(pg * 4 + j) * 512 + i4 * 4];
                    xv[j][0] = v.x; xv[j][1] = v.y; xv[j][2] = v.z; xv[j][3] = v.w;
                }
#pragma unroll
                for (int u = 0; u < 4; ++u) {
                    float4 v = *(const float4*)&W1[(size_t)(i4 * 4 + u) * 256 + cg * 4];
                    wv[u][0] = v.x; wv[u][1] = v.y; wv[u][2] = v.z; wv[u][3] = v.w;
                }
#pragma unroll
                for (int j = 0; j < 4; ++j)
#pragma unroll
                    for (int c = 0; c < 4; ++c)
#pragma unroll
                        for (int u = 0; u < 4; ++u)
                            acc[j][c] = fmaf(xv[j][u], wv[u][c], acc[j][c]);
            }
            float4 bb = *(const float4*)&b1[cg * 4];
            float h1v[4][4];
#pragma unroll
            for (int j = 0; j < 4; ++j) {
                h1v[j][0] = fmaxf(acc[j][0] + bb.x, 0.f);
                h1v[j][1] = fmaxf(acc[j][1] + bb.y, 0.f);
                h1v[j][2] = fmaxf(acc[j][2] + bb.z, 0.f);
                h1v[j][3] = fmaxf(acc[j][3] + bb.w, 0.f);
            }
            __syncthreads();   // all x reads done before overwriting xbuf with h1
#pragma unroll
            for (int j = 0; j < 4; ++j)
                *(float4*)&xbuf[(pg * 4 + j) * 256 + cg * 4] =
                    make_float4(h1v[j][0], h1v[j][1], h1v[j][2], h1v[j][3]);
        }
        __syncthreads();

        // ---------- GEMM2: h2 = relu(h1 @ W2 + b2)  [16x256]@[256x128] ----------
        {
            const int pg = tid >> 5;   // 8 groups x 2 paths
            const int cg = tid & 31;   // 32 col groups x 4 cols = 128
            float acc[2][4];
#pragma unroll
            for (int j = 0; j < 2; ++j)
#pragma unroll
                for (int c = 0; c < 4; ++c) acc[j][c] = 0.f;
            gemm_2x4<64>(&xbuf[(pg * 2 + 0) * 256], &xbuf[(pg * 2 + 1) * 256],
                         &W2[cg * 4], acc);
            float4 bb = *(const float4*)&b2[cg * 4];
#pragma unroll
            for (int j = 0; j < 2; ++j) {
                float4 hv = make_float4(fmaxf(acc[j][0] + bb.x, 0.f),
                                        fmaxf(acc[j][1] + bb.y, 0.f),
                                        fmaxf(acc[j][2] + bb.z, 0.f),
                                        fmaxf(acc[j][3] + bb.w, 0.f));
                *(float4*)&h2s[(ch * CHUNK + pg * 2 + j) * DD + cg * 4] = hv;
            }
        }
        __syncthreads();

        // ---------- GEMM3: a1 = relu(h2 @ A1[:128] + s1)  [16x128]@[128x128] ----------
        {
            const int pg = tid >> 5;
            const int cg = tid & 31;
            float acc[2][4];
#pragma unroll
            for (int c = 0; c < 4; ++c) {
                const float sv = s1[cg * 4 + c];
                acc[0][c] = sv; acc[1][c] = sv;
            }
            gemm_2x4<32>(&h2s[(ch * CHUNK + pg * 2 + 0) * DD],
                         &h2s[(ch * CHUNK + pg * 2 + 1) * DD],
                         &A1[cg * 4], acc);
#pragma unroll
            for (int j = 0; j < 2; ++j)
                *(float4*)&xbuf[4096 + (pg * 2 + j) * DD + cg * 4] =
                    make_float4(fmaxf(acc[j][0], 0.f), fmaxf(acc[j][1], 0.f),
                                fmaxf(acc[j][2], 0.f), fmaxf(acc[j][3], 0.f));
        }
        __syncthreads();

        // ---------- GEMM4: a2 = relu(a1 @ A2 + ab2)  [16x128]@[128x128] ----------
        {
            const int pg = tid >> 5;
            const int cg = tid & 31;
            float acc[2][4];
#pragma unroll
            for (int c = 0; c < 4; ++c) {
                const float bv = ab2[cg * 4 + c];
                acc[0][c] = bv; acc[1][c] = bv;
            }
            gemm_2x4<32>(&xbuf[4096 + (pg * 2 + 0) * DD],
                         &xbuf[4096 + (pg * 2 + 1) * DD],
                         &A2[cg * 4], acc);
#pragma unroll
            for (int j = 0; j < 2; ++j)
                *(float4*)&xbuf[6144 + (pg * 2 + j) * DD + cg * 4] =
                    make_float4(fmaxf(acc[j][0], 0.f), fmaxf(acc[j][1], 0.f),
                                fmaxf(acc[j][2], 0.f), fmaxf(acc[j][3], 0.f));
        }
        __syncthreads();

        // ---------- logits[k] = a2 . A3 + ab3 ----------
        {
            const int p = tid >> 4;
            const int t = tid & 15;
            const float* a2r = &xbuf[6144 + p * DD];
            float part = 0.f;
#pragma unroll
            for (int j = 0; j < 8; ++j)
                part = fmaf(a2r[t * 8 + j], a3s[t * 8 + j], part);
            part += __shfl_down(part, 8, 16);
            part += __shfl_down(part, 4, 16);
            part += __shfl_down(part, 2, 16);
            part += __shfl_down(part, 1, 16);
            if (t == 0) logits[ch * CHUNK + p] = part + ab3[0];
        }
        __syncthreads();
    }

    // ---------- softmax over 64 paths (wave 0) ----------
    if (tid < KK) {
        float l = logits[tid];
        float m = l;
#pragma unroll
        for (int off = 32; off > 0; off >>= 1) m = fmaxf(m, __shfl_xor(m, off, 64));
        float e = expf(l - m);
        float s = e;
#pragma unroll
        for (int off = 32; off > 0; off >>= 1) s += __shfl_xor(s, off, 64);
        wts[tid] = e / s;
    }
    __syncthreads();

    // ---------- out[n] = sum_k w[k] * h2[k] ----------
    if (tid < DD) {
        float acc = 0.f;
#pragma unroll 8
        for (int k = 0; k < KK; ++k)
            acc = fmaf(wts[k], h2s[k * DD + tid], acc);
        out[(size_t)n * DD + tid] = acc;
    }
}

extern "C" void kernel_launch(void* const* d_in, const int* in_sizes, int n_in,
                              void* d_out, int out_size, void* d_ws, size_t ws_size,
                              hipStream_t stream)
{
    const int*   nodes     = (const int*)d_in[0];
    const int*   paths_rel = (const int*)d_in[1];
    const int*   paths_nbr = (const int*)d_in[2];
    const int*   attrs     = (const int*)d_in[3];
    const float* u2e  = (const float*)d_in[4];
    const float* r2e  = (const float*)d_in[5];
    const float* ua2e = (const float*)d_in[6];
    const float* W1   = (const float*)d_in[7];
    const float* b1   = (const float*)d_in[8];
    const float* W2   = (const float*)d_in[9];
    const float* b2   = (const float*)d_in[10];
    const float* A1   = (const float*)d_in[11];
    const float* ab1  = (const float*)d_in[12];
    const float* A2   = (const float*)d_in[13];
    const float* ab2  = (const float*)d_in[14];
    const float* A3   = (const float*)d_in[15];
    const float* ab3  = (const float*)d_in[16];
    float* out = (float*)d_out;

    hipLaunchKernelGGL(l2agg_kernel, dim3(NN), dim3(256), 0, stream,
                       nodes, paths_rel, paths_nbr, attrs, u2e, r2e, ua2e,
                       W1, b1, W2, b2, A1, ab1, A2, ab2, A3, ab3, out);
}

// Round 2
// 864.577 us; speedup vs baseline: 2.3656x; 2.3656x over previous
//
#include <hip/hip_runtime.h>
#include <hip/hip_bf16.h>

#define NN 4096
#define KK 64
#define AA 8
#define DD 128
#define CHUNK 16
#define NCHUNK (KK / CHUNK)

#define XS_STRIDE 520   // 512 + 8 pad (bf16 elems): row stride 1040 B -> bank rotate 4/row
#define H1_STRIDE 264   // 256 + 8
#define H2_STRIDE 136   // 128 + 8
#define A_STRIDE  136
#define A2_OFF    2176  // a2 tile offset (shorts) inside xs region; 4352 B, 16B-aligned

typedef __bf16 bf16x8 __attribute__((ext_vector_type(8)));
typedef short  s16x8  __attribute__((ext_vector_type(8)));
typedef float  f32x4  __attribute__((ext_vector_type(4)));

__device__ __forceinline__ short f2bf(float f) {
    unsigned u = __builtin_bit_cast(unsigned, f);
    u += 0x7FFFu + ((u >> 16) & 1u);   // RNE
    return (short)(u >> 16);
}
__device__ __forceinline__ float bf2f(short s) {
    unsigned u = ((unsigned)(unsigned short)s) << 16;
    return __builtin_bit_cast(float, u);
}
__device__ __forceinline__ void store_bf8(short* dst, float4 a, float4 b) {
    s16x8 v;
    v[0] = f2bf(a.x); v[1] = f2bf(a.y); v[2] = f2bf(a.z); v[3] = f2bf(a.w);
    v[4] = f2bf(b.x); v[5] = f2bf(b.y); v[6] = f2bf(b.z); v[7] = f2bf(b.w);
    *(s16x8*)dst = v;
}

// Pack fp32 weight [K][Ncols] into bf16 B-fragment order for mfma_f32_16x16x32_bf16:
// dst[((ntile*Ksteps + kstep)*64 + lane)*8 + j] = src[kstep*32 + (lane>>4)*8 + j][ntile*16 + (lane&15)]
__global__ void pack_w(const float* __restrict__ src, short* __restrict__ dst,
                       int Ncols, int ks_log2, int total)
{
    int t = blockIdx.x * 256 + threadIdx.x;
    if (t >= total) return;
    int j     = t & 7;
    int lane  = (t >> 3) & 63;
    int fi    = t >> 9;
    int kstep = fi & ((1 << ks_log2) - 1);
    int ntile = fi >> ks_log2;
    int k  = kstep * 32 + (lane >> 4) * 8 + j;
    int nn = ntile * 16 + (lane & 15);
    dst[t] = f2bf(src[(size_t)k * Ncols + nn]);
}

__launch_bounds__(256, 3)
__global__ void l2agg_mfma(
    const int* __restrict__ nodes,
    const int* __restrict__ paths_rel,
    const int* __restrict__ paths_nbr,
    const int* __restrict__ attrs,
    const float* __restrict__ u2e,
    const float* __restrict__ r2e,
    const float* __restrict__ ua2e,
    const float* __restrict__ b1,
    const float* __restrict__ b2,
    const float* __restrict__ A1,    // fp32 original (rows 128.. used for s1)
    const float* __restrict__ ab1,
    const float* __restrict__ ab2,
    const float* __restrict__ A3,
    const float* __restrict__ ab3,
    const short* __restrict__ W1p,
    const short* __restrict__ W2p,
    const short* __restrict__ A1p,
    const short* __restrict__ A2p,
    float* __restrict__ out)
{
    __shared__ short xs[CHUNK * XS_STRIDE];   // 16.6 KB; reused: a1 at [0), a2 at [A2_OFF)
    __shared__ short h1s[CHUNK * H1_STRIDE];  // 8.4 KB
    __shared__ short h2s[KK * H2_STRIDE];     // 17.4 KB, persists to final reduce
    __shared__ float selfe[DD];
    __shared__ float s1f[DD];
    __shared__ float a3s[DD];
    __shared__ float logits[KK];
    __shared__ float wts[KK];

    const int n    = blockIdx.x;
    const int tid  = threadIdx.x;
    const int node = nodes[n];

    if (tid < 32) {
        *(float4*)&selfe[tid * 4] = *(const float4*)&u2e[(size_t)node * DD + tid * 4];
        *(float4*)&a3s[tid * 4]   = *(const float4*)&A3[tid * 4];
    }
    __syncthreads();

    // s1 = ab1 + selfe @ A1[128:256, :]  (fp32, once per node)
    if (tid < DD) {
        float acc = ab1[tid];
#pragma unroll 4
        for (int i = 0; i < DD; ++i)
            acc = fmaf(selfe[i], A1[(size_t)(DD + i) * DD + tid], acc);
        s1f[tid] = acc;
    }

    const int lane = tid & 63;
    const int wv   = tid >> 6;    // wave 0..3
    const int mr   = lane & 15;   // A-row / C-col index
    const int q    = lane >> 4;   // quad

    for (int ch = 0; ch < NCHUNK; ++ch) {
        // ---------- stage x[16][512] (fp32 gathers -> bf16 LDS) ----------
        {
            const int p  = tid >> 4;
            const int t  = tid & 15;
            const int k  = ch * CHUNK + p;
            const int pk = n * KK + k;
            const int i0 = paths_rel[pk * 2 + 0];
            const int i1 = paths_rel[pk * 2 + 1];
            const int nb = paths_nbr[pk];
            const int o  = t * 8;

            float4 r1a = *(const float4*)&r2e[(size_t)i0 * DD + o];
            float4 r1b = *(const float4*)&r2e[(size_t)i0 * DD + o + 4];
            float4 r2a = *(const float4*)&r2e[(size_t)i1 * DD + o];
            float4 r2b = *(const float4*)&r2e[(size_t)i1 * DD + o + 4];
            float4 nea = *(const float4*)&u2e[(size_t)nb * DD + o];
            float4 neb = *(const float4*)&u2e[(size_t)nb * DD + o + 4];
            float4 aea = make_float4(0.f, 0.f, 0.f, 0.f);
            float4 aeb = make_float4(0.f, 0.f, 0.f, 0.f);
#pragma unroll
            for (int a = 0; a < AA; ++a) {
                const int ai = attrs[pk * AA + a];
                float4 va = *(const float4*)&ua2e[(size_t)ai * DD + o];
                float4 vb = *(const float4*)&ua2e[(size_t)ai * DD + o + 4];
                aea.x += va.x; aea.y += va.y; aea.z += va.z; aea.w += va.w;
                aeb.x += vb.x; aeb.y += vb.y; aeb.z += vb.z; aeb.w += vb.w;
            }
            short* xr = &xs[p * XS_STRIDE];
            store_bf8(&xr[o],       r1a, r1b);
            store_bf8(&xr[128 + o], r2a, r2b);
            store_bf8(&xr[256 + o], nea, neb);
            store_bf8(&xr[384 + o], aea, aeb);
        }
        __syncthreads();

        // ---------- GEMM1: h1 = relu(x @ W1 + b1), wave wv -> cols [wv*64, wv*64+64) ----------
        {
            f32x4 acc[4] = {};
#pragma unroll 4
            for (int ks = 0; ks < 16; ++ks) {
                bf16x8 af = *(const bf16x8*)&xs[mr * XS_STRIDE + ks * 32 + q * 8];
#pragma unroll
                for (int t4 = 0; t4 < 4; ++t4) {
                    bf16x8 bf = *(const bf16x8*)&W1p[(((wv * 4 + t4) * 16 + ks) * 64 + lane) * 8];
                    acc[t4] = __builtin_amdgcn_mfma_f32_16x16x32_bf16(af, bf, acc[t4], 0, 0, 0);
                }
            }
#pragma unroll
            for (int t4 = 0; t4 < 4; ++t4) {
                const int col = (wv * 4 + t4) * 16 + mr;
                const float bb = b1[col];
#pragma unroll
                for (int r = 0; r < 4; ++r) {
                    float v = fmaxf(acc[t4][r] + bb, 0.f);
                    h1s[(q * 4 + r) * H1_STRIDE + col] = f2bf(v);
                }
            }
        }
        __syncthreads();

        // ---------- GEMM2: h2 = relu(h1 @ W2 + b2), wave wv -> cols [wv*32, wv*32+32) ----------
        {
            f32x4 acc[2] = {};
#pragma unroll 4
            for (int ks = 0; ks < 8; ++ks) {
                bf16x8 af = *(const bf16x8*)&h1s[mr * H1_STRIDE + ks * 32 + q * 8];
#pragma unroll
                for (int t2 = 0; t2 < 2; ++t2) {
                    bf16x8 bf = *(const bf16x8*)&W2p[(((wv * 2 + t2) * 8 + ks) * 64 + lane) * 8];
                    acc[t2] = __builtin_amdgcn_mfma_f32_16x16x32_bf16(af, bf, acc[t2], 0, 0, 0);
                }
            }
#pragma unroll
            for (int t2 = 0; t2 < 2; ++t2) {
                const int col = (wv * 2 + t2) * 16 + mr;
                const float bb = b2[col];
#pragma unroll
                for (int r = 0; r < 4; ++r) {
                    float v = fmaxf(acc[t2][r] + bb, 0.f);
                    h2s[(ch * CHUNK + q * 4 + r) * H2_STRIDE + col] = f2bf(v);
                }
            }
        }
        __syncthreads();

        // ---------- GEMM3: a1 = relu(h2 @ A1[:128] + s1) -> xs[0..) ----------
        {
            f32x4 acc[2];
#pragma unroll
            for (int t2 = 0; t2 < 2; ++t2) {
                const float sv = s1f[(wv * 2 + t2) * 16 + mr];
                acc[t2][0] = sv; acc[t2][1] = sv; acc[t2][2] = sv; acc[t2][3] = sv;
            }
#pragma unroll
            for (int ks = 0; ks < 4; ++ks) {
                bf16x8 af = *(const bf16x8*)&h2s[(ch * CHUNK + mr) * H2_STRIDE + ks * 32 + q * 8];
#pragma unroll
                for (int t2 = 0; t2 < 2; ++t2) {
                    bf16x8 bf = *(const bf16x8*)&A1p[(((wv * 2 + t2) * 4 + ks) * 64 + lane) * 8];
                    acc[t2] = __builtin_amdgcn_mfma_f32_16x16x32_bf16(af, bf, acc[t2], 0, 0, 0);
                }
            }
#pragma unroll
            for (int t2 = 0; t2 < 2; ++t2) {
                const int col = (wv * 2 + t2) * 16 + mr;
#pragma unroll
                for (int r = 0; r < 4; ++r)
                    xs[(q * 4 + r) * A_STRIDE + col] = f2bf(fmaxf(acc[t2][r], 0.f));
            }
        }
        __syncthreads();

        // ---------- GEMM4: a2 = relu(a1 @ A2 + ab2) -> xs[A2_OFF..) ----------
        {
            f32x4 acc[2];
#pragma unroll
            for (int t2 = 0; t2 < 2; ++t2) {
                const float bv = ab2[(wv * 2 + t2) * 16 + mr];
                acc[t2][0] = bv; acc[t2][1] = bv; acc[t2][2] = bv; acc[t2][3] = bv;
            }
#pragma unroll
            for (int ks = 0; ks < 4; ++ks) {
                bf16x8 af = *(const bf16x8*)&xs[mr * A_STRIDE + ks * 32 + q * 8];
#pragma unroll
                for (int t2 = 0; t2 < 2; ++t2) {
                    bf16x8 bf = *(const bf16x8*)&A2p[(((wv * 2 + t2) * 4 + ks) * 64 + lane) * 8];
                    acc[t2] = __builtin_amdgcn_mfma_f32_16x16x32_bf16(af, bf, acc[t2], 0, 0, 0);
                }
            }
#pragma unroll
            for (int t2 = 0; t2 < 2; ++t2) {
                const int col = (wv * 2 + t2) * 16 + mr;
#pragma unroll
                for (int r = 0; r < 4; ++r)
                    xs[A2_OFF + (q * 4 + r) * A_STRIDE + col] = f2bf(fmaxf(acc[t2][r], 0.f));
            }
        }
        __syncthreads();

        // ---------- logits[k] = a2 . A3 + ab3 ----------
        {
            const int p = tid >> 4;
            const int t = tid & 15;
            const short* a2r = &xs[A2_OFF + p * A_STRIDE];
            float part = 0.f;
#pragma unroll
            for (int j = 0; j < 8; ++j)
                part = fmaf(bf2f(a2r[t * 8 + j]), a3s[t * 8 + j], part);
            part += __shfl_down(part, 8, 16);
            part += __shfl_down(part, 4, 16);
            part += __shfl_down(part, 2, 16);
            part += __shfl_down(part, 1, 16);
            if (t == 0) logits[ch * CHUNK + p] = part + ab3[0];
        }
        __syncthreads();
    }

    // ---------- softmax over 64 paths ----------
    if (tid < KK) {
        float l = logits[tid];
        float m = l;
#pragma unroll
        for (int off = 32; off > 0; off >>= 1) m = fmaxf(m, __shfl_xor(m, off, 64));
        float e = expf(l - m);
        float s = e;
#pragma unroll
        for (int off = 32; off > 0; off >>= 1) s += __shfl_xor(s, off, 64);
        wts[tid] = e / s;
    }
    __syncthreads();

    // ---------- out[n] = sum_k w[k] * h2[k] ----------
    if (tid < DD) {
        float acc = 0.f;
#pragma unroll 8
        for (int k = 0; k < KK; ++k)
            acc = fmaf(wts[k], bf2f(h2s[k * H2_STRIDE + tid]), acc);
        out[(size_t)n * DD + tid] = acc;
    }
}

extern "C" void kernel_launch(void* const* d_in, const int* in_sizes, int n_in,
                              void* d_out, int out_size, void* d_ws, size_t ws_size,
                              hipStream_t stream)
{
    const int*   nodes     = (const int*)d_in[0];
    const int*   paths_rel = (const int*)d_in[1];
    const int*   paths_nbr = (const int*)d_in[2];
    const int*   attrs     = (const int*)d_in[3];
    const float* u2e  = (const float*)d_in[4];
    const float* r2e  = (const float*)d_in[5];
    const float* ua2e = (const float*)d_in[6];
    const float* W1   = (const float*)d_in[7];
    const float* b1   = (const float*)d_in[8];
    const float* W2   = (const float*)d_in[9];
    const float* b2   = (const float*)d_in[10];
    const float* A1   = (const float*)d_in[11];
    const float* ab1  = (const float*)d_in[12];
    const float* A2   = (const float*)d_in[13];
    const float* ab2  = (const float*)d_in[14];
    const float* A3   = (const float*)d_in[15];
    const float* ab3  = (const float*)d_in[16];
    float* out = (float*)d_out;

    // ws layout (shorts): W1p 131072 | W2p 32768 | A1p 16384 | A2p 16384  = 384 KB
    short* wsp = (short*)d_ws;
    short* W1p = wsp;
    short* W2p = wsp + 131072;
    short* A1p = wsp + 163840;
    short* A2p = wsp + 180224;

    hipLaunchKernelGGL(pack_w, dim3(512), dim3(256), 0, stream, W1, W1p, 256, 4, 131072);
    hipLaunchKernelGGL(pack_w, dim3(128), dim3(256), 0, stream, W2, W2p, 128, 3, 32768);
    hipLaunchKernelGGL(pack_w, dim3(64),  dim3(256), 0, stream, A1, A1p, 128, 2, 16384);
    hipLaunchKernelGGL(pack_w, dim3(64),  dim3(256), 0, stream, A2, A2p, 128, 2, 16384);

    hipLaunchKernelGGL(l2agg_mfma, dim3(NN), dim3(256), 0, stream,
                       nodes, paths_rel, paths_nbr, attrs, u2e, r2e, ua2e,
                       b1, b2, A1, ab1, ab2, A3, ab3,
                       W1p, W2p, A1p, A2p, out);
}

// Round 3
// 506.875 us; speedup vs baseline: 4.0349x; 1.7057x over previous
//
#include <hip/hip_runtime.h>
#include <hip/hip_bf16.h>

#define NN 4096
#define KK 64
#define AA 8
#define DD 128

// LDS region1 (shorts): x-halves / h1 use stride 264 (64 rows);
// a1 at offset 0 stride 136; a2 at offset 8704 stride 136.
#define R1_SIZE   17408
#define XH_STRIDE 264
#define A_STRIDE  136
#define A2_OFF    8704
#define H2_STRIDE 136

typedef __bf16 bf16x8 __attribute__((ext_vector_type(8)));
typedef short  s16x8  __attribute__((ext_vector_type(8)));
typedef float  f32x4  __attribute__((ext_vector_type(4)));

__device__ __forceinline__ short f2bf(float f) {
    unsigned u = __builtin_bit_cast(unsigned, f);
    u += 0x7FFFu + ((u >> 16) & 1u);   // RNE
    return (short)(u >> 16);
}
__device__ __forceinline__ float bf2f(short s) {
    unsigned u = ((unsigned)(unsigned short)s) << 16;
    return __builtin_bit_cast(float, u);
}
__device__ __forceinline__ void store_bf8(short* dst, float4 a, float4 b) {
    s16x8 v;
    v[0] = f2bf(a.x); v[1] = f2bf(a.y); v[2] = f2bf(a.z); v[3] = f2bf(a.w);
    v[4] = f2bf(b.x); v[5] = f2bf(b.y); v[6] = f2bf(b.z); v[7] = f2bf(b.w);
    *(s16x8*)dst = v;
}

// Pack fp32 weight [K][Ncols] into bf16 B-fragment order for mfma_f32_16x16x32_bf16:
// dst[((ntile*Ksteps + kstep)*64 + lane)*8 + j] = src[kstep*32 + (lane>>4)*8 + j][ntile*16 + (lane&15)]
__global__ void pack_w(const float* __restrict__ src, short* __restrict__ dst,
                       int Ncols, int ks_log2, int total)
{
    int t = blockIdx.x * 256 + threadIdx.x;
    if (t >= total) return;
    int j     = t & 7;
    int lane  = (t >> 3) & 63;
    int fi    = t >> 9;
    int kstep = fi & ((1 << ks_log2) - 1);
    int ntile = fi >> ks_log2;
    int k  = kstep * 32 + (lane >> 4) * 8 + j;
    int nn = ntile * 16 + (lane & 15);
    dst[t] = f2bf(src[(size_t)k * Ncols + nn]);
}

__launch_bounds__(256, 3)
__global__ void l2agg_mfma(
    const int* __restrict__ nodes,
    const int* __restrict__ paths_rel,
    const int* __restrict__ paths_nbr,
    const int* __restrict__ attrs,
    const float* __restrict__ u2e,
    const float* __restrict__ r2e,
    const float* __restrict__ ua2e,
    const float* __restrict__ b1,
    const float* __restrict__ b2,
    const float* __restrict__ A1,    // fp32 original (rows 128.. used for s1)
    const float* __restrict__ ab1,
    const float* __restrict__ ab2,
    const float* __restrict__ A3,
    const float* __restrict__ ab3,
    const short* __restrict__ W1p,
    const short* __restrict__ W2p,
    const short* __restrict__ A1p,
    const short* __restrict__ A2p,
    float* __restrict__ out)
{
    __shared__ short reg1[R1_SIZE];        // 34.8 KB
    __shared__ short h2s[KK * H2_STRIDE];  // 17.4 KB, persists to final reduce
    __shared__ float selfe[DD];
    __shared__ float s1f[DD];
    __shared__ float a3s[DD];
    __shared__ float logits[KK];
    __shared__ float wts[KK];

    const int n    = blockIdx.x;
    const int tid  = threadIdx.x;
    const int node = nodes[n];

    if (tid < 32) {
        *(float4*)&selfe[tid * 4] = *(const float4*)&u2e[(size_t)node * DD + tid * 4];
        *(float4*)&a3s[tid * 4]   = *(const float4*)&A3[tid * 4];
    }

    const int lane = tid & 63;
    const int wv   = tid >> 6;    // wave 0..3
    const int mr   = lane & 15;   // A-row / C-col index within 16-tile
    const int q    = lane >> 4;   // quad

    // ---------- stage xA = [r1 | r2] for all 64 paths (k 0..255) ----------
#pragma unroll
    for (int pass = 0; pass < 4; ++pass) {
        const int p  = pass * 16 + (tid >> 4);
        const int t  = tid & 15;
        const int o  = t * 8;
        const int pk = n * KK + p;
        const int i0 = paths_rel[pk * 2 + 0];
        const int i1 = paths_rel[pk * 2 + 1];
        float4 r1a = *(const float4*)&r2e[(size_t)i0 * DD + o];
        float4 r1b = *(const float4*)&r2e[(size_t)i0 * DD + o + 4];
        float4 r2a = *(const float4*)&r2e[(size_t)i1 * DD + o];
        float4 r2b = *(const float4*)&r2e[(size_t)i1 * DD + o + 4];
        store_bf8(&reg1[p * XH_STRIDE + o], r1a, r1b);
        store_bf8(&reg1[p * XH_STRIDE + 128 + o], r2a, r2b);
    }
    __syncthreads();   // b1

    // s1 = ab1 + selfe @ A1[128:256, :]  (waves 0-1; overlaps waves 2-3 MFMA)
    if (tid < DD) {
        float acc = ab1[tid];
#pragma unroll 4
        for (int i = 0; i < DD; ++i)
            acc = fmaf(selfe[i], A1[(size_t)(DD + i) * DD + tid], acc);
        s1f[tid] = acc;
    }

    // ---------- GEMM1 half 1: ks 0..7 over xA ----------
    f32x4 acc1[4][4] = {};
#pragma unroll
    for (int ks = 0; ks < 8; ++ks) {
        bf16x8 af[4];
#pragma unroll
        for (int mt = 0; mt < 4; ++mt)
            af[mt] = *(const bf16x8*)&reg1[(mt * 16 + mr) * XH_STRIDE + ks * 32 + q * 8];
#pragma unroll
        for (int nt = 0; nt < 4; ++nt) {
            bf16x8 bf = *(const bf16x8*)&W1p[(((wv * 4 + nt) * 16 + ks) * 64 + lane) * 8];
#pragma unroll
            for (int mt = 0; mt < 4; ++mt)
                acc1[mt][nt] = __builtin_amdgcn_mfma_f32_16x16x32_bf16(af[mt], bf, acc1[mt][nt], 0, 0, 0);
        }
    }
    __syncthreads();   // b2: xA fully consumed

    // ---------- stage xB = [ne | ae] for all 64 paths (k 256..511) ----------
#pragma unroll
    for (int pass = 0; pass < 4; ++pass) {
        const int p  = pass * 16 + (tid >> 4);
        const int t  = tid & 15;
        const int o  = t * 8;
        const int pk = n * KK + p;
        const int nb = paths_nbr[pk];
        float4 nea = *(const float4*)&u2e[(size_t)nb * DD + o];
        float4 neb = *(const float4*)&u2e[(size_t)nb * DD + o + 4];
        float4 aea = make_float4(0.f, 0.f, 0.f, 0.f);
        float4 aeb = make_float4(0.f, 0.f, 0.f, 0.f);
#pragma unroll
        for (int a = 0; a < AA; ++a) {
            const int ai = attrs[pk * AA + a];
            float4 va = *(const float4*)&ua2e[(size_t)ai * DD + o];
            float4 vb = *(const float4*)&ua2e[(size_t)ai * DD + o + 4];
            aea.x += va.x; aea.y += va.y; aea.z += va.z; aea.w += va.w;
            aeb.x += vb.x; aeb.y += vb.y; aeb.z += vb.z; aeb.w += vb.w;
        }
        store_bf8(&reg1[p * XH_STRIDE + o], nea, neb);
        store_bf8(&reg1[p * XH_STRIDE + 128 + o], aea, aeb);
    }
    __syncthreads();   // b3

    // ---------- GEMM1 half 2: ks 8..15 over xB ----------
#pragma unroll
    for (int ks2 = 0; ks2 < 8; ++ks2) {
        bf16x8 af[4];
#pragma unroll
        for (int mt = 0; mt < 4; ++mt)
            af[mt] = *(const bf16x8*)&reg1[(mt * 16 + mr) * XH_STRIDE + ks2 * 32 + q * 8];
#pragma unroll
        for (int nt = 0; nt < 4; ++nt) {
            bf16x8 bf = *(const bf16x8*)&W1p[(((wv * 4 + nt) * 16 + 8 + ks2) * 64 + lane) * 8];
#pragma unroll
            for (int mt = 0; mt < 4; ++mt)
                acc1[mt][nt] = __builtin_amdgcn_mfma_f32_16x16x32_bf16(af[mt], bf, acc1[mt][nt], 0, 0, 0);
        }
    }
    __syncthreads();   // b4: xB fully consumed before h1 overwrite

    // ---------- h1 = relu(acc1 + b1) -> reg1 (stride 264, bf16) ----------
#pragma unroll
    for (int nt = 0; nt < 4; ++nt) {
        const int col = (wv * 4 + nt) * 16 + mr;
        const float bb = b1[col];
#pragma unroll
        for (int mt = 0; mt < 4; ++mt)
#pragma unroll
            for (int r = 0; r < 4; ++r)
                reg1[(mt * 16 + q * 4 + r) * XH_STRIDE + col] =
                    f2bf(fmaxf(acc1[mt][nt][r] + bb, 0.f));
    }
    __syncthreads();   // b5

    // ---------- GEMM2: h2 = relu(h1 @ W2 + b2) ----------
    {
        f32x4 acc[4][2] = {};
#pragma unroll
        for (int ks = 0; ks < 8; ++ks) {
            bf16x8 af[4];
#pragma unroll
            for (int mt = 0; mt < 4; ++mt)
                af[mt] = *(const bf16x8*)&reg1[(mt * 16 + mr) * XH_STRIDE + ks * 32 + q * 8];
#pragma unroll
            for (int nt = 0; nt < 2; ++nt) {
                bf16x8 bf = *(const bf16x8*)&W2p[(((wv * 2 + nt) * 8 + ks) * 64 + lane) * 8];
#pragma unroll
                for (int mt = 0; mt < 4; ++mt)
                    acc[mt][nt] = __builtin_amdgcn_mfma_f32_16x16x32_bf16(af[mt], bf, acc[mt][nt], 0, 0, 0);
            }
        }
#pragma unroll
        for (int nt = 0; nt < 2; ++nt) {
            const int col = (wv * 2 + nt) * 16 + mr;
            const float bb = b2[col];
#pragma unroll
            for (int mt = 0; mt < 4; ++mt)
#pragma unroll
                for (int r = 0; r < 4; ++r)
                    h2s[(mt * 16 + q * 4 + r) * H2_STRIDE + col] =
                        f2bf(fmaxf(acc[mt][nt][r] + bb, 0.f));
        }
    }
    __syncthreads();   // b6

    // ---------- GEMM3: a1 = relu(h2 @ A1[:128] + s1) -> reg1[0..) stride 136 ----------
    {
        f32x4 acc[4][2];
#pragma unroll
        for (int nt = 0; nt < 2; ++nt) {
            const float sv = s1f[(wv * 2 + nt) * 16 + mr];
#pragma unroll
            for (int mt = 0; mt < 4; ++mt) {
                acc[mt][nt][0] = sv; acc[mt][nt][1] = sv;
                acc[mt][nt][2] = sv; acc[mt][nt][3] = sv;
            }
        }
#pragma unroll
        for (int ks = 0; ks < 4; ++ks) {
            bf16x8 af[4];
#pragma unroll
            for (int mt = 0; mt < 4; ++mt)
                af[mt] = *(const bf16x8*)&h2s[(mt * 16 + mr) * H2_STRIDE + ks * 32 + q * 8];
#pragma unroll
            for (int nt = 0; nt < 2; ++nt) {
                bf16x8 bf = *(const bf16x8*)&A1p[(((wv * 2 + nt) * 4 + ks) * 64 + lane) * 8];
#pragma unroll
                for (int mt = 0; mt < 4; ++mt)
                    acc[mt][nt] = __builtin_amdgcn_mfma_f32_16x16x32_bf16(af[mt], bf, acc[mt][nt], 0, 0, 0);
            }
        }
#pragma unroll
        for (int nt = 0; nt < 2; ++nt) {
            const int col = (wv * 2 + nt) * 16 + mr;
#pragma unroll
            for (int mt = 0; mt < 4; ++mt)
#pragma unroll
                for (int r = 0; r < 4; ++r)
                    reg1[(mt * 16 + q * 4 + r) * A_STRIDE + col] =
                        f2bf(fmaxf(acc[mt][nt][r], 0.f));
        }
    }
    __syncthreads();   // b7

    // ---------- GEMM4: a2 = relu(a1 @ A2 + ab2) -> reg1[A2_OFF..) ----------
    {
        f32x4 acc[4][2];
#pragma unroll
        for (int nt = 0; nt < 2; ++nt) {
            const float bv = ab2[(wv * 2 + nt) * 16 + mr];
#pragma unroll
            for (int mt = 0; mt < 4; ++mt) {
                acc[mt][nt][0] = bv; acc[mt][nt][1] = bv;
                acc[mt][nt][2] = bv; acc[mt][nt][3] = bv;
            }
        }
#pragma unroll
        for (int ks = 0; ks < 4; ++ks) {
            bf16x8 af[4];
#pragma unroll
            for (int mt = 0; mt < 4; ++mt)
                af[mt] = *(const bf16x8*)&reg1[(mt * 16 + mr) * A_STRIDE + ks * 32 + q * 8];
#pragma unroll
            for (int nt = 0; nt < 2; ++nt) {
                bf16x8 bf = *(const bf16x8*)&A2p[(((wv * 2 + nt) * 4 + ks) * 64 + lane) * 8];
#pragma unroll
                for (int mt = 0; mt < 4; ++mt)
                    acc[mt][nt] = __builtin_amdgcn_mfma_f32_16x16x32_bf16(af[mt], bf, acc[mt][nt], 0, 0, 0);
            }
        }
#pragma unroll
        for (int nt = 0; nt < 2; ++nt) {
            const int col = (wv * 2 + nt) * 16 + mr;
#pragma unroll
            for (int mt = 0; mt < 4; ++mt)
#pragma unroll
                for (int r = 0; r < 4; ++r)
                    reg1[A2_OFF + (mt * 16 + q * 4 + r) * A_STRIDE + col] =
                        f2bf(fmaxf(acc[mt][nt][r], 0.f));
        }
    }
    __syncthreads();   // b8

    // ---------- logits[p] = a2[p] . A3 + ab3 ----------
#pragma unroll
    for (int pass = 0; pass < 4; ++pass) {
        const int p = pass * 16 + (tid >> 4);
        const int t = tid & 15;
        const short* a2r = &reg1[A2_OFF + p * A_STRIDE];
        float part = 0.f;
#pragma unroll
        for (int j = 0; j < 8; ++j)
            part = fmaf(bf2f(a2r[t * 8 + j]), a3s[t * 8 + j], part);
        part += __shfl_down(part, 8, 16);
        part += __shfl_down(part, 4, 16);
        part += __shfl_down(part, 2, 16);
        part += __shfl_down(part, 1, 16);
        if (t == 0) logits[p] = part + ab3[0];
    }
    __syncthreads();   // b9

    // ---------- softmax over 64 paths ----------
    if (tid < KK) {
        float l = logits[tid];
        float m = l;
#pragma unroll
        for (int off = 32; off > 0; off >>= 1) m = fmaxf(m, __shfl_xor(m, off, 64));
        float e = expf(l - m);
        float s = e;
#pragma unroll
        for (int off = 32; off > 0; off >>= 1) s += __shfl_xor(s, off, 64);
        wts[tid] = e / s;
    }
    __syncthreads();

    // ---------- out[n] = sum_k w[k] * h2[k] ----------
    if (tid < DD) {
        float acc = 0.f;
#pragma unroll 8
        for (int k = 0; k < KK; ++k)
            acc = fmaf(wts[k], bf2f(h2s[k * H2_STRIDE + tid]), acc);
        out[(size_t)n * DD + tid] = acc;
    }
}

extern "C" void kernel_launch(void* const* d_in, const int* in_sizes, int n_in,
                              void* d_out, int out_size, void* d_ws, size_t ws_size,
                              hipStream_t stream)
{
    const int*   nodes     = (const int*)d_in[0];
    const int*   paths_rel = (const int*)d_in[1];
    const int*   paths_nbr = (const int*)d_in[2];
    const int*   attrs     = (const int*)d_in[3];
    const float* u2e  = (const float*)d_in[4];
    const float* r2e  = (const float*)d_in[5];
    const float* ua2e = (const float*)d_in[6];
    const float* W1   = (const float*)d_in[7];
    const float* b1   = (const float*)d_in[8];
    const float* W2   = (const float*)d_in[9];
    const float* b2   = (const float*)d_in[10];
    const float* A1   = (const float*)d_in[11];
    const float* ab1  = (const float*)d_in[12];
    const float* A2   = (const float*)d_in[13];
    const float* ab2  = (const float*)d_in[14];
    const float* A3   = (const float*)d_in[15];
    const float* ab3  = (const float*)d_in[16];
    float* out = (float*)d_out;

    // ws layout (shorts): W1p 131072 | W2p 32768 | A1p 16384 | A2p 16384  = 384 KB
    short* wsp = (short*)d_ws;
    short* W1p = wsp;
    short* W2p = wsp + 131072;
    short* A1p = wsp + 163840;
    short* A2p = wsp + 180224;

    hipLaunchKernelGGL(pack_w, dim3(512), dim3(256), 0, stream, W1, W1p, 256, 4, 131072);
    hipLaunchKernelGGL(pack_w, dim3(128), dim3(256), 0, stream, W2, W2p, 128, 3, 32768);
    hipLaunchKernelGGL(pack_w, dim3(64),  dim3(256), 0, stream, A1, A1p, 128, 2, 16384);
    hipLaunchKernelGGL(pack_w, dim3(64),  dim3(256), 0, stream, A2, A2p, 128, 2, 16384);

    hipLaunchKernelGGL(l2agg_mfma, dim3(NN), dim3(256), 0, stream,
                       nodes, paths_rel, paths_nbr, attrs, u2e, r2e, ua2e,
                       b1, b2, A1, ab1, ab2, A3, ab3,
                       W1p, W2p, A1p, A2p, out);
}

// Round 4
// 334.273 us; speedup vs baseline: 6.1184x; 1.5164x over previous
//
#include <hip/hip_runtime.h>
#include <hip/hip_bf16.h>

#define NN 4096
#define KK 64
#define AA 8
#define DD 128

#define R1_SIZE   17408
#define XH_STRIDE 264
#define A_STRIDE  136
#define A2_OFF    8704
#define H2_STRIDE 136

typedef __bf16 bf16x8 __attribute__((ext_vector_type(8)));
typedef short  s16x8  __attribute__((ext_vector_type(8)));
typedef float  f32x4  __attribute__((ext_vector_type(4)));

__device__ __forceinline__ short f2bf(float f) {
    unsigned u = __builtin_bit_cast(unsigned, f);
    u += 0x7FFFu + ((u >> 16) & 1u);   // RNE
    return (short)(u >> 16);
}
__device__ __forceinline__ float bf2f(short s) {
    unsigned u = ((unsigned)(unsigned short)s) << 16;
    return __builtin_bit_cast(float, u);
}
__device__ __forceinline__ void store_bf8(short* dst, float4 a, float4 b) {
    s16x8 v;
    v[0] = f2bf(a.x); v[1] = f2bf(a.y); v[2] = f2bf(a.z); v[3] = f2bf(a.w);
    v[4] = f2bf(b.x); v[5] = f2bf(b.y); v[6] = f2bf(b.z); v[7] = f2bf(b.w);
    *(s16x8*)dst = v;
}

// All four weight packs in one launch. Fragment order for mfma_f32_16x16x32_bf16 B:
// dst[((ntile*Ksteps + kstep)*64 + lane)*8 + j] = src[kstep*32+(lane>>4)*8+j][ntile*16+(lane&15)]
__global__ void pack_all(const float* __restrict__ W1, const float* __restrict__ W2,
                         const float* __restrict__ A1, const float* __restrict__ A2,
                         short* __restrict__ W1p, short* __restrict__ W2p,
                         short* __restrict__ A1p, short* __restrict__ A2p)
{
    int t = blockIdx.x * 256 + threadIdx.x;
    const float* src; short* dst; int Ncols, ksl, idx;
    if (t < 131072)      { src = W1; dst = W1p; Ncols = 256; ksl = 4; idx = t; }
    else if (t < 163840) { src = W2; dst = W2p; Ncols = 128; ksl = 3; idx = t - 131072; }
    else if (t < 180224) { src = A1; dst = A1p; Ncols = 128; ksl = 2; idx = t - 163840; }
    else                 { src = A2; dst = A2p; Ncols = 128; ksl = 2; idx = t - 180224; }
    int j     = idx & 7;
    int lane  = (idx >> 3) & 63;
    int fi    = idx >> 9;
    int kstep = fi & ((1 << ksl) - 1);
    int ntile = fi >> ksl;
    int k  = kstep * 32 + (lane >> 4) * 8 + j;
    int nn = ntile * 16 + (lane & 15);
    dst[idx] = f2bf(src[(size_t)k * Ncols + nn]);
}

// s1[n] = ab1 + u2e[nodes[n]] @ A1[128:256,:]  for all nodes (hoisted out of hot kernel)
__global__ void prep_s1(const int* __restrict__ nodes, const float* __restrict__ u2e,
                        const float* __restrict__ A1, const float* __restrict__ ab1,
                        float* __restrict__ s1g)
{
    __shared__ float row[DD];
    const int n = blockIdx.x, c = threadIdx.x;
    const int node = nodes[n];
    row[c] = u2e[(size_t)node * DD + c];
    __syncthreads();
    float acc = ab1[c];
#pragma unroll 8
    for (int i = 0; i < DD; ++i)
        acc = fmaf(row[i], A1[(size_t)(DD + i) * DD + c], acc);
    s1g[(size_t)n * DD + c] = acc;
}

__launch_bounds__(256, 3)
__global__ void l2agg_mfma(
    const int* __restrict__ paths_rel,
    const int* __restrict__ paths_nbr,
    const int* __restrict__ attrs,
    const float* __restrict__ u2e,
    const float* __restrict__ r2e,
    const float* __restrict__ ua2e,
    const float* __restrict__ b1,
    const float* __restrict__ b2,
    const float* __restrict__ ab2,
    const float* __restrict__ A3,
    const float* __restrict__ ab3,
    const short* __restrict__ W1p,
    const short* __restrict__ W2p,
    const short* __restrict__ A1p,
    const short* __restrict__ A2p,
    const float* __restrict__ s1g,
    float* __restrict__ out)
{
    __shared__ short reg1[R1_SIZE];        // 34.8 KB: x/h1 (stride 264) -> a1[0..8704) + a2[8704..)
    __shared__ short h2s[KK * H2_STRIDE];  // 17.4 KB, persists to final reduce
    __shared__ int   idx_lds[KK * AA + KK]; // 2304 B: attrs (512) + nbr (64), DMA-prefetched
    // logits/wts alias the dead a1 region at the end:
    float* logits = (float*)&reg1[0];      // 64 floats
    float* wts    = (float*)&reg1[128];    // 64 floats

    const int n    = blockIdx.x;
    const int tid  = threadIdx.x;
    const int lane = tid & 63;
    const int wv   = tid >> 6;
    const int mr   = lane & 15;
    const int q    = lane >> 4;

    // ---------- async DMA prefetch: attrs + nbr indices -> LDS (consumed after b2) ----------
    {
        const int* ab = attrs + (size_t)n * KK * AA;
        __builtin_amdgcn_global_load_lds(
            (const __attribute__((address_space(1))) void*)(ab + wv * 128 + lane),
            (__attribute__((address_space(3))) void*)(idx_lds + wv * 128), 4, 0, 0);
        __builtin_amdgcn_global_load_lds(
            (const __attribute__((address_space(1))) void*)(ab + wv * 128 + 64 + lane),
            (__attribute__((address_space(3))) void*)(idx_lds + wv * 128 + 64), 4, 0, 0);
        if (wv == 0) {
            const int* nb = paths_nbr + (size_t)n * KK;
            __builtin_amdgcn_global_load_lds(
                (const __attribute__((address_space(1))) void*)(nb + lane),
                (__attribute__((address_space(3))) void*)(idx_lds + 512), 4, 0, 0);
        }
    }

    // ---------- stage xA = [r1 | r2] for 64 paths ----------
#pragma unroll
    for (int pass = 0; pass < 4; ++pass) {
        const int p  = pass * 16 + (tid >> 4);
        const int t  = tid & 15;
        const int o  = t * 8;
        const int pk = n * KK + p;
        const int i0 = paths_rel[pk * 2 + 0];
        const int i1 = paths_rel[pk * 2 + 1];
        float4 r1a = *(const float4*)&r2e[(size_t)i0 * DD + o];
        float4 r1b = *(const float4*)&r2e[(size_t)i0 * DD + o + 4];
        float4 r2a = *(const float4*)&r2e[(size_t)i1 * DD + o];
        float4 r2b = *(const float4*)&r2e[(size_t)i1 * DD + o + 4];
        store_bf8(&reg1[p * XH_STRIDE + o], r1a, r1b);
        store_bf8(&reg1[p * XH_STRIDE + 128 + o], r2a, r2b);
    }
    __syncthreads();   // b1

    // ---------- GEMM1 half 1 (ks 0..7), 2-deep B prefetch ----------
    const short* W1b = W1p + wv * 32768 + lane * 8;   // frag(nt,ks) = W1b[nt*8192 + ks*512]
    f32x4 acc1[4][4] = {};
    bf16x8 bfc[4], bfn[4];
#pragma unroll
    for (int nt = 0; nt < 4; ++nt) bfc[nt] = *(const bf16x8*)&W1b[nt * 8192];
#pragma unroll
    for (int ks = 0; ks < 8; ++ks) {
#pragma unroll
        for (int nt = 0; nt < 4; ++nt)
            bfn[nt] = *(const bf16x8*)&W1b[nt * 8192 + (ks + 1) * 512];
        bf16x8 af[4];
#pragma unroll
        for (int mt = 0; mt < 4; ++mt)
            af[mt] = *(const bf16x8*)&reg1[(mt * 16 + mr) * XH_STRIDE + ks * 32 + q * 8];
#pragma unroll
        for (int nt = 0; nt < 4; ++nt)
#pragma unroll
            for (int mt = 0; mt < 4; ++mt)
                acc1[mt][nt] = __builtin_amdgcn_mfma_f32_16x16x32_bf16(af[mt], bfc[nt], acc1[mt][nt], 0, 0, 0);
#pragma unroll
        for (int nt = 0; nt < 4; ++nt) bfc[nt] = bfn[nt];   // ks=7 carries ks=8 frags across staging
    }
    __syncthreads();   // b2

    // ---------- stage xB = [ne | ae]; indices from LDS (already landed) ----------
#pragma unroll
    for (int pass = 0; pass < 4; ++pass) {
        const int p  = pass * 16 + (tid >> 4);
        const int t  = tid & 15;
        const int o  = t * 8;
        const int nb = idx_lds[512 + p];
        float4 nea = *(const float4*)&u2e[(size_t)nb * DD + o];
        float4 neb = *(const float4*)&u2e[(size_t)nb * DD + o + 4];
        float4 aea = make_float4(0.f, 0.f, 0.f, 0.f);
        float4 aeb = make_float4(0.f, 0.f, 0.f, 0.f);
#pragma unroll
        for (int a = 0; a < AA; ++a) {
            const int ai = idx_lds[p * AA + a];
            float4 va = *(const float4*)&ua2e[(size_t)ai * DD + o];
            float4 vb = *(const float4*)&ua2e[(size_t)ai * DD + o + 4];
            aea.x += va.x; aea.y += va.y; aea.z += va.z; aea.w += va.w;
            aeb.x += vb.x; aeb.y += vb.y; aeb.z += vb.z; aeb.w += vb.w;
        }
        store_bf8(&reg1[p * XH_STRIDE + o], nea, neb);
        store_bf8(&reg1[p * XH_STRIDE + 128 + o], aea, aeb);
    }
    __syncthreads();   // b3

    // ---------- GEMM1 half 2 (ks 8..15) ----------
#pragma unroll
    for (int ks = 8; ks < 16; ++ks) {
        if (ks < 15) {
#pragma unroll
            for (int nt = 0; nt < 4; ++nt)
                bfn[nt] = *(const bf16x8*)&W1b[nt * 8192 + (ks + 1) * 512];
        }
        bf16x8 af[4];
#pragma unroll
        for (int mt = 0; mt < 4; ++mt)
            af[mt] = *(const bf16x8*)&reg1[(mt * 16 + mr) * XH_STRIDE + (ks - 8) * 32 + q * 8];
#pragma unroll
        for (int nt = 0; nt < 4; ++nt)
#pragma unroll
            for (int mt = 0; mt < 4; ++mt)
                acc1[mt][nt] = __builtin_amdgcn_mfma_f32_16x16x32_bf16(af[mt], bfc[nt], acc1[mt][nt], 0, 0, 0);
        if (ks < 15) {
#pragma unroll
            for (int nt = 0; nt < 4; ++nt) bfc[nt] = bfn[nt];
        }
    }

    // preload GEMM2 ks=0 B-frags (in flight across b4/epilogue/b5)
    const short* W2b = W2p + wv * 8192 + lane * 8;    // frag(nt,ks) = W2b[nt*4096 + ks*512]
    bf16x8 g2c[2], g2n[2];
    g2c[0] = *(const bf16x8*)&W2b[0];
    g2c[1] = *(const bf16x8*)&W2b[4096];
    __syncthreads();   // b4: xB consumed, reg1 free for h1

    // ---------- h1 = relu(acc1 + b1) -> reg1 ----------
#pragma unroll
    for (int nt = 0; nt < 4; ++nt) {
        const int col = (wv * 4 + nt) * 16 + mr;
        const float bb = b1[col];
#pragma unroll
        for (int mt = 0; mt < 4; ++mt)
#pragma unroll
            for (int r = 0; r < 4; ++r)
                reg1[(mt * 16 + q * 4 + r) * XH_STRIDE + col] =
                    f2bf(fmaxf(acc1[mt][nt][r] + bb, 0.f));
    }
    __syncthreads();   // b5

    // ---------- GEMM2: h2 = relu(h1 @ W2 + b2), 2-deep B prefetch ----------
    f32x4 acc2[4][2] = {};
#pragma unroll
    for (int ks = 0; ks < 8; ++ks) {
        if (ks < 7) {
            g2n[0] = *(const bf16x8*)&W2b[(ks + 1) * 512];
            g2n[1] = *(const bf16x8*)&W2b[4096 + (ks + 1) * 512];
        }
        bf16x8 af[4];
#pragma unroll
        for (int mt = 0; mt < 4; ++mt)
            af[mt] = *(const bf16x8*)&reg1[(mt * 16 + mr) * XH_STRIDE + ks * 32 + q * 8];
#pragma unroll
        for (int nt = 0; nt < 2; ++nt)
#pragma unroll
            for (int mt = 0; mt < 4; ++mt)
                acc2[mt][nt] = __builtin_amdgcn_mfma_f32_16x16x32_bf16(af[mt], g2c[nt], acc2[mt][nt], 0, 0, 0);
        if (ks < 7) { g2c[0] = g2n[0]; g2c[1] = g2n[1]; }
    }

    // preload ALL GEMM3 B-frags + s1 values (hidden under GEMM2 epilogue + b6)
    const short* A1b = A1p + wv * 4096 + lane * 8;    // frag(nt,ks) = A1b[nt*2048 + ks*512]
    bf16x8 g3f[2][4];
#pragma unroll
    for (int nt = 0; nt < 2; ++nt)
#pragma unroll
        for (int ks = 0; ks < 4; ++ks)
            g3f[nt][ks] = *(const bf16x8*)&A1b[nt * 2048 + ks * 512];
    float s1v[2];
    s1v[0] = s1g[(size_t)n * DD + (wv * 2 + 0) * 16 + mr];
    s1v[1] = s1g[(size_t)n * DD + (wv * 2 + 1) * 16 + mr];

    // GEMM2 epilogue -> h2s
#pragma unroll
    for (int nt = 0; nt < 2; ++nt) {
        const int col = (wv * 2 + nt) * 16 + mr;
        const float bb = b2[col];
#pragma unroll
        for (int mt = 0; mt < 4; ++mt)
#pragma unroll
            for (int r = 0; r < 4; ++r)
                h2s[(mt * 16 + q * 4 + r) * H2_STRIDE + col] =
                    f2bf(fmaxf(acc2[mt][nt][r] + bb, 0.f));
    }
    __syncthreads();   // b6

    // ---------- GEMM3: a1 = relu(h2 @ A1[:128] + s1) -> reg1[0..8704) ----------
    {
        f32x4 acc[4][2];
#pragma unroll
        for (int nt = 0; nt < 2; ++nt)
#pragma unroll
            for (int mt = 0; mt < 4; ++mt) {
                acc[mt][nt][0] = s1v[nt]; acc[mt][nt][1] = s1v[nt];
                acc[mt][nt][2] = s1v[nt]; acc[mt][nt][3] = s1v[nt];
            }
#pragma unroll
        for (int ks = 0; ks < 4; ++ks) {
            bf16x8 af[4];
#pragma unroll
            for (int mt = 0; mt < 4; ++mt)
                af[mt] = *(const bf16x8*)&h2s[(mt * 16 + mr) * H2_STRIDE + ks * 32 + q * 8];
#pragma unroll
            for (int nt = 0; nt < 2; ++nt)
#pragma unroll
                for (int mt = 0; mt < 4; ++mt)
                    acc[mt][nt] = __builtin_amdgcn_mfma_f32_16x16x32_bf16(af[mt], g3f[nt][ks], acc[mt][nt], 0, 0, 0);
        }
        // preload ALL GEMM4 B-frags (hidden under GEMM3 epilogue + b7)
        const short* A2b = A2p + wv * 4096 + lane * 8;
        bf16x8 g4f[2][4];
#pragma unroll
        for (int nt = 0; nt < 2; ++nt)
#pragma unroll
            for (int ks = 0; ks < 4; ++ks)
                g4f[nt][ks] = *(const bf16x8*)&A2b[nt * 2048 + ks * 512];

#pragma unroll
        for (int nt = 0; nt < 2; ++nt) {
            const int col = (wv * 2 + nt) * 16 + mr;
#pragma unroll
            for (int mt = 0; mt < 4; ++mt)
#pragma unroll
                for (int r = 0; r < 4; ++r)
                    reg1[(mt * 16 + q * 4 + r) * A_STRIDE + col] =
                        f2bf(fmaxf(acc[mt][nt][r], 0.f));
        }
        __syncthreads();   // b7

        // ---------- GEMM4: a2 = relu(a1 @ A2 + ab2) -> reg1[A2_OFF..) ----------
        f32x4 acc4[4][2];
#pragma unroll
        for (int nt = 0; nt < 2; ++nt) {
            const float bv = ab2[(wv * 2 + nt) * 16 + mr];
#pragma unroll
            for (int mt = 0; mt < 4; ++mt) {
                acc4[mt][nt][0] = bv; acc4[mt][nt][1] = bv;
                acc4[mt][nt][2] = bv; acc4[mt][nt][3] = bv;
            }
        }
#pragma unroll
        for (int ks = 0; ks < 4; ++ks) {
            bf16x8 af[4];
#pragma unroll
            for (int mt = 0; mt < 4; ++mt)
                af[mt] = *(const bf16x8*)&reg1[(mt * 16 + mr) * A_STRIDE + ks * 32 + q * 8];
#pragma unroll
            for (int nt = 0; nt < 2; ++nt)
#pragma unroll
                for (int mt = 0; mt < 4; ++mt)
                    acc4[mt][nt] = __builtin_amdgcn_mfma_f32_16x16x32_bf16(af[mt], g4f[nt][ks], acc4[mt][nt], 0, 0, 0);
        }
#pragma unroll
        for (int nt = 0; nt < 2; ++nt) {
            const int col = (wv * 2 + nt) * 16 + mr;
#pragma unroll
            for (int mt = 0; mt < 4; ++mt)
#pragma unroll
                for (int r = 0; r < 4; ++r)
                    reg1[A2_OFF + (mt * 16 + q * 4 + r) * A_STRIDE + col] =
                        f2bf(fmaxf(acc4[mt][nt][r], 0.f));
        }
    }
    __syncthreads();   // b8

    // ---------- logits[p] = a2[p] . A3 + ab3  (A3 from cache) ----------
    {
        const int t = tid & 15;
        float4 a3a = *(const float4*)&A3[t * 8];
        float4 a3b = *(const float4*)&A3[t * 8 + 4];
#pragma unroll
        for (int pass = 0; pass < 4; ++pass) {
            const int p = pass * 16 + (tid >> 4);
            const short* a2r = &reg1[A2_OFF + p * A_STRIDE];
            float part = bf2f(a2r[t * 8 + 0]) * a3a.x;
            part = fmaf(bf2f(a2r[t * 8 + 1]), a3a.y, part);
            part = fmaf(bf2f(a2r[t * 8 + 2]), a3a.z, part);
            part = fmaf(bf2f(a2r[t * 8 + 3]), a3a.w, part);
            part = fmaf(bf2f(a2r[t * 8 + 4]), a3b.x, part);
            part = fmaf(bf2f(a2r[t * 8 + 5]), a3b.y, part);
            part = fmaf(bf2f(a2r[t * 8 + 6]), a3b.z, part);
            part = fmaf(bf2f(a2r[t * 8 + 7]), a3b.w, part);
            part += __shfl_down(part, 8, 16);
            part += __shfl_down(part, 4, 16);
            part += __shfl_down(part, 2, 16);
            part += __shfl_down(part, 1, 16);
            if (t == 0) logits[p] = part + ab3[0];   // a1 region dead; alias safe
        }
    }
    __syncthreads();   // b9

    // ---------- softmax over 64 paths ----------
    if (tid < KK) {
        float l = logits[tid];
        float m = l;
#pragma unroll
        for (int off = 32; off > 0; off >>= 1) m = fmaxf(m, __shfl_xor(m, off, 64));
        float e = expf(l - m);
        float s = e;
#pragma unroll
        for (int off = 32; off > 0; off >>= 1) s += __shfl_xor(s, off, 64);
        wts[tid] = e / s;
    }
    __syncthreads();   // b10

    // ---------- out[n] = sum_k w[k] * h2[k] ----------
    if (tid < DD) {
        float acc = 0.f;
#pragma unroll 8
        for (int k = 0; k < KK; ++k)
            acc = fmaf(wts[k], bf2f(h2s[k * H2_STRIDE + tid]), acc);
        out[(size_t)n * DD + tid] = acc;
    }
}

extern "C" void kernel_launch(void* const* d_in, const int* in_sizes, int n_in,
                              void* d_out, int out_size, void* d_ws, size_t ws_size,
                              hipStream_t stream)
{
    const int*   nodes     = (const int*)d_in[0];
    const int*   paths_rel = (const int*)d_in[1];
    const int*   paths_nbr = (const int*)d_in[2];
    const int*   attrs     = (const int*)d_in[3];
    const float* u2e  = (const float*)d_in[4];
    const float* r2e  = (const float*)d_in[5];
    const float* ua2e = (const float*)d_in[6];
    const float* W1   = (const float*)d_in[7];
    const float* b1   = (const float*)d_in[8];
    const float* W2   = (const float*)d_in[9];
    const float* b2   = (const float*)d_in[10];
    const float* A1   = (const float*)d_in[11];
    const float* ab1  = (const float*)d_in[12];
    const float* A2   = (const float*)d_in[13];
    const float* ab2  = (const float*)d_in[14];
    const float* A3   = (const float*)d_in[15];
    const float* ab3  = (const float*)d_in[16];
    float* out = (float*)d_out;

    // ws layout: shorts W1p 131072 | W2p 32768 | A1p 16384 | A2p 16384 (=384 KB),
    // then s1g float[4096*128] (2 MB)
    short* wsp = (short*)d_ws;
    short* W1p = wsp;
    short* W2p = wsp + 131072;
    short* A1p = wsp + 163840;
    short* A2p = wsp + 180224;
    float* s1g = (float*)((char*)d_ws + 393216);

    hipLaunchKernelGGL(pack_all, dim3(768), dim3(256), 0, stream,
                       W1, W2, A1, A2, W1p, W2p, A1p, A2p);
    hipLaunchKernelGGL(prep_s1, dim3(NN), dim3(DD), 0, stream,
                       nodes, u2e, A1, ab1, s1g);
    hipLaunchKernelGGL(l2agg_mfma, dim3(NN), dim3(256), 0, stream,
                       paths_rel, paths_nbr, attrs, u2e, r2e, ua2e,
                       b1, b2, ab2, A3, ab3,
                       W1p, W2p, A1p, A2p, s1g, out);
}

// Round 5
// 297.598 us; speedup vs baseline: 6.8724x; 1.1232x over previous
//
#include <hip/hip_runtime.h>
#include <hip/hip_bf16.h>

#define NN 4096
#define KK 64
#define AA 8
#define DD 128

// reg1 (shorts): x-halves / h1 use stride 264 (64 rows x 256 + 8 pad, 16B-aligned rows);
// a1 reuses first 8704 shorts at stride 136.
#define R1_SIZE   16896
#define XH_STRIDE 264
#define A_STRIDE  136
#define H2_STRIDE 136

typedef __bf16 bf16x8 __attribute__((ext_vector_type(8)));
typedef short  s16x8  __attribute__((ext_vector_type(8)));
typedef float  f32x4  __attribute__((ext_vector_type(4)));

__device__ __forceinline__ short f2bf(float f) {
    unsigned u = __builtin_bit_cast(unsigned, f);
    u += 0x7FFFu + ((u >> 16) & 1u);   // RNE
    return (short)(u >> 16);
}
__device__ __forceinline__ float bf2f(short s) {
    unsigned u = ((unsigned)(unsigned short)s) << 16;
    return __builtin_bit_cast(float, u);
}
__device__ __forceinline__ void store_bf8(short* dst, float4 a, float4 b) {
    s16x8 v;
    v[0] = f2bf(a.x); v[1] = f2bf(a.y); v[2] = f2bf(a.z); v[3] = f2bf(a.w);
    v[4] = f2bf(b.x); v[5] = f2bf(b.y); v[6] = f2bf(b.z); v[7] = f2bf(b.w);
    *(s16x8*)dst = v;
}

// All four weight packs in one launch. Fragment order for mfma_f32_16x16x32_bf16 B:
// dst[((ntile*Ksteps + kstep)*64 + lane)*8 + j] = src[kstep*32+(lane>>4)*8+j][ntile*16+(lane&15)]
__global__ void pack_all(const float* __restrict__ W1, const float* __restrict__ W2,
                         const float* __restrict__ A1, const float* __restrict__ A2,
                         short* __restrict__ W1p, short* __restrict__ W2p,
                         short* __restrict__ A1p, short* __restrict__ A2p)
{
    int t = blockIdx.x * 256 + threadIdx.x;
    const float* src; short* dst; int Ncols, ksl, idx;
    if (t < 131072)      { src = W1; dst = W1p; Ncols = 256; ksl = 4; idx = t; }
    else if (t < 163840) { src = W2; dst = W2p; Ncols = 128; ksl = 3; idx = t - 131072; }
    else if (t < 180224) { src = A1; dst = A1p; Ncols = 128; ksl = 2; idx = t - 163840; }
    else                 { src = A2; dst = A2p; Ncols = 128; ksl = 2; idx = t - 180224; }
    int j     = idx & 7;
    int lane  = (idx >> 3) & 63;
    int fi    = idx >> 9;
    int kstep = fi & ((1 << ksl) - 1);
    int ntile = fi >> ksl;
    int k  = kstep * 32 + (lane >> 4) * 8 + j;
    int nn = ntile * 16 + (lane & 15);
    dst[idx] = f2bf(src[(size_t)k * Ncols + nn]);
}

// s1[n] = ab1 + u2e[nodes[n]] @ A1[128:256,:]  for all nodes
__global__ void prep_s1(const int* __restrict__ nodes, const float* __restrict__ u2e,
                        const float* __restrict__ A1, const float* __restrict__ ab1,
                        float* __restrict__ s1g)
{
    __shared__ float row[DD];
    const int n = blockIdx.x, c = threadIdx.x;
    const int node = nodes[n];
    row[c] = u2e[(size_t)node * DD + c];
    __syncthreads();
    float acc = ab1[c];
#pragma unroll 8
    for (int i = 0; i < DD; ++i)
        acc = fmaf(row[i], A1[(size_t)(DD + i) * DD + c], acc);
    s1g[(size_t)n * DD + c] = acc;
}

__launch_bounds__(512, 4)
__global__ void l2agg_mfma(
    const int* __restrict__ paths_rel,
    const int* __restrict__ paths_nbr,
    const int* __restrict__ attrs,
    const float* __restrict__ u2e,
    const float* __restrict__ r2e,
    const float* __restrict__ ua2e,
    const float* __restrict__ b1,
    const float* __restrict__ b2,
    const float* __restrict__ ab2,
    const float* __restrict__ A3,
    const float* __restrict__ ab3,
    const short* __restrict__ W1p,
    const short* __restrict__ W2p,
    const short* __restrict__ A1p,
    const short* __restrict__ A2p,
    const float* __restrict__ s1g,
    float* __restrict__ out)
{
    __shared__ short reg1[R1_SIZE];          // 33.8 KB: x halves / h1 (stride 264) -> a1 (stride 136)
    __shared__ short h2s[KK * H2_STRIDE];    // 17.4 KB, persists to final reduce
    __shared__ int   idx_lds[KK * AA + KK];  // 2304 B: attrs (512) + nbr (64), DMA-prefetched
    __shared__ float partials[8 * KK];       // 2 KB: per-wave logit partials
    __shared__ float wts[KK];

    const int n    = blockIdx.x;
    const int tid  = threadIdx.x;
    const int lane = tid & 63;
    const int wv   = tid >> 6;    // wave 0..7
    const int mr   = lane & 15;
    const int q    = lane >> 4;

    // ---------- async DMA prefetch: attrs + nbr indices -> LDS (consumed after b2) ----------
    {
        const int* ab = attrs + (size_t)n * KK * AA;
        __builtin_amdgcn_global_load_lds(
            (const __attribute__((address_space(1))) void*)(ab + wv * 64 + lane),
            (__attribute__((address_space(3))) void*)(idx_lds + wv * 64), 4, 0, 0);
        if (wv == 0) {
            const int* nb = paths_nbr + (size_t)n * KK;
            __builtin_amdgcn_global_load_lds(
                (const __attribute__((address_space(1))) void*)(nb + lane),
                (__attribute__((address_space(3))) void*)(idx_lds + 512), 4, 0, 0);
        }
    }

    // ---------- stage xA = [r1 | r2] for 64 paths (2 passes of 32 paths) ----------
#pragma unroll
    for (int pass = 0; pass < 2; ++pass) {
        const int p  = pass * 32 + (tid >> 4);
        const int t  = tid & 15;
        const int o  = t * 8;
        const int pk = n * KK + p;
        const int i0 = paths_rel[pk * 2 + 0];
        const int i1 = paths_rel[pk * 2 + 1];
        float4 r1a = *(const float4*)&r2e[(size_t)i0 * DD + o];
        float4 r1b = *(const float4*)&r2e[(size_t)i0 * DD + o + 4];
        float4 r2a = *(const float4*)&r2e[(size_t)i1 * DD + o];
        float4 r2b = *(const float4*)&r2e[(size_t)i1 * DD + o + 4];
        store_bf8(&reg1[p * XH_STRIDE + o], r1a, r1b);
        store_bf8(&reg1[p * XH_STRIDE + 128 + o], r2a, r2b);
    }
    __syncthreads();   // b1

    // ---------- GEMM1 half 1 (ks 0..7), wave -> cols wv*32..wv*32+31 (2 ntiles) ----------
    const short* W1b = W1p + wv * 2 * 16 * 512 + lane * 8;  // frag(nt,ks) = W1b[nt*8192 + ks*512]
    f32x4 acc1[4][2] = {};
    bf16x8 bfc[2], bfn[2];
#pragma unroll
    for (int nt = 0; nt < 2; ++nt) bfc[nt] = *(const bf16x8*)&W1b[nt * 8192];
#pragma unroll
    for (int ks = 0; ks < 8; ++ks) {
#pragma unroll
        for (int nt = 0; nt < 2; ++nt)
            bfn[nt] = *(const bf16x8*)&W1b[nt * 8192 + (ks + 1) * 512];
        bf16x8 af[4];
#pragma unroll
        for (int mt = 0; mt < 4; ++mt)
            af[mt] = *(const bf16x8*)&reg1[(mt * 16 + mr) * XH_STRIDE + ks * 32 + q * 8];
#pragma unroll
        for (int nt = 0; nt < 2; ++nt)
#pragma unroll
            for (int mt = 0; mt < 4; ++mt)
                acc1[mt][nt] = __builtin_amdgcn_mfma_f32_16x16x32_bf16(af[mt], bfc[nt], acc1[mt][nt], 0, 0, 0);
#pragma unroll
        for (int nt = 0; nt < 2; ++nt) bfc[nt] = bfn[nt];   // ks=7 carries ks=8 frags across staging
    }
    __syncthreads();   // b2

    // ---------- stage xB = [ne | ae]; indices from LDS ----------
#pragma unroll
    for (int pass = 0; pass < 2; ++pass) {
        const int p  = pass * 32 + (tid >> 4);
        const int t  = tid & 15;
        const int o  = t * 8;
        const int nb = idx_lds[512 + p];
        float4 nea = *(const float4*)&u2e[(size_t)nb * DD + o];
        float4 neb = *(const float4*)&u2e[(size_t)nb * DD + o + 4];
        float4 aea = make_float4(0.f, 0.f, 0.f, 0.f);
        float4 aeb = make_float4(0.f, 0.f, 0.f, 0.f);
#pragma unroll
        for (int a = 0; a < AA; ++a) {
            const int ai = idx_lds[p * AA + a];
            float4 va = *(const float4*)&ua2e[(size_t)ai * DD + o];
            float4 vb = *(const float4*)&ua2e[(size_t)ai * DD + o + 4];
            aea.x += va.x; aea.y += va.y; aea.z += va.z; aea.w += va.w;
            aeb.x += vb.x; aeb.y += vb.y; aeb.z += vb.z; aeb.w += vb.w;
        }
        store_bf8(&reg1[p * XH_STRIDE + o], nea, neb);
        store_bf8(&reg1[p * XH_STRIDE + 128 + o], aea, aeb);
    }
    __syncthreads();   // b3

    // ---------- GEMM1 half 2 (ks 8..15) ----------
#pragma unroll
    for (int ks = 8; ks < 16; ++ks) {
        if (ks < 15) {
#pragma unroll
            for (int nt = 0; nt < 2; ++nt)
                bfn[nt] = *(const bf16x8*)&W1b[nt * 8192 + (ks + 1) * 512];
        }
        bf16x8 af[4];
#pragma unroll
        for (int mt = 0; mt < 4; ++mt)
            af[mt] = *(const bf16x8*)&reg1[(mt * 16 + mr) * XH_STRIDE + (ks - 8) * 32 + q * 8];
#pragma unroll
        for (int nt = 0; nt < 2; ++nt)
#pragma unroll
            for (int mt = 0; mt < 4; ++mt)
                acc1[mt][nt] = __builtin_amdgcn_mfma_f32_16x16x32_bf16(af[mt], bfc[nt], acc1[mt][nt], 0, 0, 0);
        if (ks < 15) {
#pragma unroll
            for (int nt = 0; nt < 2; ++nt) bfc[nt] = bfn[nt];
        }
    }

    // preload GEMM2 ks=0 B-frag (in flight across b4/epilogue/b5); wave -> cols wv*16..wv*16+15
    const short* W2b = W2p + wv * 8 * 512 + lane * 8;       // frag(ks) = W2b[ks*512]
    bf16x8 g2c = *(const bf16x8*)&W2b[0], g2n;
    __syncthreads();   // b4: xB consumed, reg1 free for h1

    // ---------- h1 = relu(acc1 + b1) -> reg1 (stride 264) ----------
#pragma unroll
    for (int nt = 0; nt < 2; ++nt) {
        const int col = (wv * 2 + nt) * 16 + mr;
        const float bb = b1[col];
#pragma unroll
        for (int mt = 0; mt < 4; ++mt)
#pragma unroll
            for (int r = 0; r < 4; ++r)
                reg1[(mt * 16 + q * 4 + r) * XH_STRIDE + col] =
                    f2bf(fmaxf(acc1[mt][nt][r] + bb, 0.f));
    }
    __syncthreads();   // b5

    // ---------- GEMM2: h2 = relu(h1 @ W2 + b2), 2-deep B prefetch ----------
    f32x4 acc2[4] = {};
#pragma unroll
    for (int ks = 0; ks < 8; ++ks) {
        if (ks < 7) g2n = *(const bf16x8*)&W2b[(ks + 1) * 512];
        bf16x8 af[4];
#pragma unroll
        for (int mt = 0; mt < 4; ++mt)
            af[mt] = *(const bf16x8*)&reg1[(mt * 16 + mr) * XH_STRIDE + ks * 32 + q * 8];
#pragma unroll
        for (int mt = 0; mt < 4; ++mt)
            acc2[mt] = __builtin_amdgcn_mfma_f32_16x16x32_bf16(af[mt], g2c, acc2[mt], 0, 0, 0);
        if (ks < 7) g2c = g2n;
    }

    // preload ALL GEMM3 B-frags + s1 (hidden under GEMM2 epilogue + b6)
    const short* A1b = A1p + wv * 4 * 512 + lane * 8;
    bf16x8 g3f[4];
#pragma unroll
    for (int ks = 0; ks < 4; ++ks) g3f[ks] = *(const bf16x8*)&A1b[ks * 512];
    const float s1v = s1g[(size_t)n * DD + wv * 16 + mr];

    // GEMM2 epilogue -> h2s (wave covers cols wv*16..+15)
    {
        const int col = wv * 16 + mr;
        const float bb = b2[col];
#pragma unroll
        for (int mt = 0; mt < 4; ++mt)
#pragma unroll
            for (int r = 0; r < 4; ++r)
                h2s[(mt * 16 + q * 4 + r) * H2_STRIDE + col] =
                    f2bf(fmaxf(acc2[mt][r] + bb, 0.f));
    }
    __syncthreads();   // b6

    // ---------- GEMM3: a1 = relu(h2 @ A1[:128] + s1) -> reg1 (stride 136) ----------
    {
        f32x4 acc3[4];
#pragma unroll
        for (int mt = 0; mt < 4; ++mt) {
            acc3[mt][0] = s1v; acc3[mt][1] = s1v; acc3[mt][2] = s1v; acc3[mt][3] = s1v;
        }
#pragma unroll
        for (int ks = 0; ks < 4; ++ks) {
            bf16x8 af[4];
#pragma unroll
            for (int mt = 0; mt < 4; ++mt)
                af[mt] = *(const bf16x8*)&h2s[(mt * 16 + mr) * H2_STRIDE + ks * 32 + q * 8];
#pragma unroll
            for (int mt = 0; mt < 4; ++mt)
                acc3[mt] = __builtin_amdgcn_mfma_f32_16x16x32_bf16(af[mt], g3f[ks], acc3[mt], 0, 0, 0);
        }
        // preload ALL GEMM4 B-frags (hidden under GEMM3 epilogue + b7)
        const short* A2b = A2p + wv * 4 * 512 + lane * 8;
        bf16x8 g4f[4];
#pragma unroll
        for (int ks = 0; ks < 4; ++ks) g4f[ks] = *(const bf16x8*)&A2b[ks * 512];

        {
            const int col = wv * 16 + mr;
#pragma unroll
            for (int mt = 0; mt < 4; ++mt)
#pragma unroll
                for (int r = 0; r < 4; ++r)
                    reg1[(mt * 16 + q * 4 + r) * A_STRIDE + col] =
                        f2bf(fmaxf(acc3[mt][r], 0.f));
        }
        __syncthreads();   // b7

        // ---------- GEMM4 + in-register logits ----------
        f32x4 acc4[4];
        {
            const float bv = ab2[wv * 16 + mr];
#pragma unroll
            for (int mt = 0; mt < 4; ++mt) {
                acc4[mt][0] = bv; acc4[mt][1] = bv; acc4[mt][2] = bv; acc4[mt][3] = bv;
            }
        }
#pragma unroll
        for (int ks = 0; ks < 4; ++ks) {
            bf16x8 af[4];
#pragma unroll
            for (int mt = 0; mt < 4; ++mt)
                af[mt] = *(const bf16x8*)&reg1[(mt * 16 + mr) * A_STRIDE + ks * 32 + q * 8];
#pragma unroll
            for (int mt = 0; mt < 4; ++mt)
                acc4[mt] = __builtin_amdgcn_mfma_f32_16x16x32_bf16(af[mt], g4f[ks], acc4[mt], 0, 0, 0);
        }
        // logit partial: relu(a2) * A3[col], reduced over the 16-lane col group
        const float av = A3[wv * 16 + mr];
        float pl[4][4];
#pragma unroll
        for (int mt = 0; mt < 4; ++mt)
#pragma unroll
            for (int r = 0; r < 4; ++r)
                pl[mt][r] = fmaxf(acc4[mt][r], 0.f) * av;
#pragma unroll
        for (int off = 1; off < 16; off <<= 1)
#pragma unroll
            for (int mt = 0; mt < 4; ++mt)
#pragma unroll
                for (int r = 0; r < 4; ++r)
                    pl[mt][r] += __shfl_xor(pl[mt][r], off, 64);
        if (mr == 0) {
#pragma unroll
            for (int mt = 0; mt < 4; ++mt)
#pragma unroll
                for (int r = 0; r < 4; ++r)
                    partials[wv * KK + mt * 16 + q * 4 + r] = pl[mt][r];
        }
    }
    __syncthreads();   // b8

    // ---------- logits sum + softmax (wave 0) ----------
    if (tid < KK) {
        float l = ab3[0];
#pragma unroll
        for (int w = 0; w < 8; ++w) l += partials[w * KK + tid];
        float m = l;
#pragma unroll
        for (int off = 32; off > 0; off >>= 1) m = fmaxf(m, __shfl_xor(m, off, 64));
        float e = expf(l - m);
        float s = e;
#pragma unroll
        for (int off = 32; off > 0; off >>= 1) s += __shfl_xor(s, off, 64);
        wts[tid] = e / s;
    }
    __syncthreads();   // b9

    // ---------- out[n] = sum_k w[k] * h2[k] ----------
    if (tid < DD) {
        float acc = 0.f;
#pragma unroll 8
        for (int k = 0; k < KK; ++k)
            acc = fmaf(wts[k], bf2f(h2s[k * H2_STRIDE + tid]), acc);
        out[(size_t)n * DD + tid] = acc;
    }
}

extern "C" void kernel_launch(void* const* d_in, const int* in_sizes, int n_in,
                              void* d_out, int out_size, void* d_ws, size_t ws_size,
                              hipStream_t stream)
{
    const int*   nodes     = (const int*)d_in[0];
    const int*   paths_rel = (const int*)d_in[1];
    const int*   paths_nbr = (const int*)d_in[2];
    const int*   attrs     = (const int*)d_in[3];
    const float* u2e  = (const float*)d_in[4];
    const float* r2e  = (const float*)d_in[5];
    const float* ua2e = (const float*)d_in[6];
    const float* W1   = (const float*)d_in[7];
    const float* b1   = (const float*)d_in[8];
    const float* W2   = (const float*)d_in[9];
    const float* b2   = (const float*)d_in[10];
    const float* A1   = (const float*)d_in[11];
    const float* ab1  = (const float*)d_in[12];
    const float* A2   = (const float*)d_in[13];
    const float* ab2  = (const float*)d_in[14];
    const float* A3   = (const float*)d_in[15];
    const float* ab3  = (const float*)d_in[16];
    float* out = (float*)d_out;

    // ws layout: shorts W1p 131072 | W2p 32768 | A1p 16384 | A2p 16384 (=384 KB),
    // then s1g float[4096*128] (2 MB)
    short* wsp = (short*)d_ws;
    short* W1p = wsp;
    short* W2p = wsp + 131072;
    short* A1p = wsp + 163840;
    short* A2p = wsp + 180224;
    float* s1g = (float*)((char*)d_ws + 393216);

    hipLaunchKernelGGL(pack_all, dim3(768), dim3(256), 0, stream,
                       W1, W2, A1, A2, W1p, W2p, A1p, A2p);
    hipLaunchKernelGGL(prep_s1, dim3(NN), dim3(DD), 0, stream,
                       nodes, u2e, A1, ab1, s1g);
    hipLaunchKernelGGL(l2agg_mfma, dim3(NN), dim3(512), 0, stream,
                       paths_rel, paths_nbr, attrs, u2e, r2e, ua2e,
                       b1, b2, ab2, A3, ab3,
                       W1p, W2p, A1p, A2p, s1g, out);
}